// Round 11
// baseline (347.175 us; speedup 1.0000x reference)
//
#include <hip/hip_runtime.h>
#include <hip/hip_bf16.h>
#include <math.h>

typedef unsigned long long ull;

// Problem constants
#define BB_ 16          // images
#define PP_ 1000        // proposals per image
#define CC_ 91          // classes incl background
#define FF_ 1024        // feature dim
#define DETS_ 100
#define CAP_ 2048       // candidate capacity per image (measured ~320)
#define CAND_MAX (BB_ * CAP_)
#define SURV_CAP 2048   // NMS-survivor capacity per image
#define CLS_CAP 256     // per-(image,class) candidate capacity
#define IMG_W 800.0f
#define IMG_H 800.0f
#define OFF_ 802.0f     // max(H,W)+2
#define SCORE_TH 0.05f
#define PRE_TH 0.047f   // prepass cutoff: 3e-3 margin >> 2e-5 fp32 error bound
#define NMS_TH 0.5f
#define MIN_SZ 0.01f
#define BBOX_CLIP_D 4.135166556742356   // log(1000/16)

// ---------------------------------------------------------------------------
// Kernel 1a: fp32 prepass — 64 rows x 91 cols per block (250 blocks), finds
// rows whose max non-background softmax score could exceed 0.05 (cutoff
// 0.047, guaranteed-safe margin). Appends row indices to rowlist.
// ---------------------------------------------------------------------------
__global__ __launch_bounds__(256) void prepass_rows(
    const float* __restrict__ A, const float* __restrict__ Wc,
    const float* __restrict__ bc,
    int* __restrict__ rowlist, int* __restrict__ nrowsp)
{
    __shared__ union __align__(16) SM {
        struct { float As[16][64]; float Bs[16][96]; } t;  // 4KB + 6KB
        float Ssc[64][97];                                 // 24.8KB overlay
    } sm;

    const int tid = threadIdx.x;
    const int row0 = blockIdx.x * 64;
    const int ty4 = (tid >> 4) * 4;     // 16 row-groups x 4 rows
    const int tx6 = (tid & 15) * 6;     // 16 col-groups x 6 cols

    // A staging: 64 rows x 16 k, float4 per thread
    const int am = tid >> 2;            // row 0..63
    const int ak = (tid & 3) * 4;       // k 0,4,8,12
    // B staging: 16 k x 96 cols, 6 scalars per thread
    const int bk = tid >> 4;
    const int bn = (tid & 15) * 6;

    float acc[4][6];
#pragma unroll
    for (int i = 0; i < 4; ++i)
#pragma unroll
        for (int j = 0; j < 6; ++j) acc[i][j] = 0.f;

    // prologue prefetch (k0 = 0)
    float4 avP = *reinterpret_cast<const float4*>(
        A + (size_t)(row0 + am) * FF_ + ak);
    float bvP[6];
#pragma unroll
    for (int jj = 0; jj < 6; ++jj) {
        const int c = bn + jj;
        bvP[jj] = (c < CC_) ? Wc[(size_t)bk * CC_ + c] : 0.f;
    }

    for (int k0 = 0; k0 < FF_; k0 += 16) {
        sm.t.As[ak + 0][am] = avP.x;
        sm.t.As[ak + 1][am] = avP.y;
        sm.t.As[ak + 2][am] = avP.z;
        sm.t.As[ak + 3][am] = avP.w;
#pragma unroll
        for (int jj = 0; jj < 6; ++jj) sm.t.Bs[bk][bn + jj] = bvP[jj];

        const int kn = k0 + 16;
        if (kn < FF_) {
            avP = *reinterpret_cast<const float4*>(
                A + (size_t)(row0 + am) * FF_ + kn + ak);
#pragma unroll
            for (int jj = 0; jj < 6; ++jj) {
                const int c = bn + jj;
                bvP[jj] = (c < CC_) ? Wc[(size_t)(kn + bk) * CC_ + c] : 0.f;
            }
        }
        __syncthreads();

#pragma unroll
        for (int k = 0; k < 16; ++k) {
            const float4 a4 = *reinterpret_cast<const float4*>(&sm.t.As[k][ty4]);
            const float2 b01 = *reinterpret_cast<const float2*>(&sm.t.Bs[k][tx6 + 0]);
            const float2 b23 = *reinterpret_cast<const float2*>(&sm.t.Bs[k][tx6 + 2]);
            const float2 b45 = *reinterpret_cast<const float2*>(&sm.t.Bs[k][tx6 + 4]);
            const float a0 = a4.x, a1 = a4.y, a2 = a4.z, a3 = a4.w;
            acc[0][0] += a0 * b01.x; acc[0][1] += a0 * b01.y;
            acc[0][2] += a0 * b23.x; acc[0][3] += a0 * b23.y;
            acc[0][4] += a0 * b45.x; acc[0][5] += a0 * b45.y;
            acc[1][0] += a1 * b01.x; acc[1][1] += a1 * b01.y;
            acc[1][2] += a1 * b23.x; acc[1][3] += a1 * b23.y;
            acc[1][4] += a1 * b45.x; acc[1][5] += a1 * b45.y;
            acc[2][0] += a2 * b01.x; acc[2][1] += a2 * b01.y;
            acc[2][2] += a2 * b23.x; acc[2][3] += a2 * b23.y;
            acc[2][4] += a2 * b45.x; acc[2][5] += a2 * b45.y;
            acc[3][0] += a3 * b01.x; acc[3][1] += a3 * b01.y;
            acc[3][2] += a3 * b23.x; acc[3][3] += a3 * b23.y;
            acc[3][4] += a3 * b45.x; acc[3][5] += a3 * b45.y;
        }
        __syncthreads();
    }

    // approx logits into overlay
#pragma unroll
    for (int i = 0; i < 4; ++i)
#pragma unroll
        for (int j = 0; j < 6; ++j) {
            const int c = tx6 + j;
            if (c < CC_) sm.Ssc[ty4 + i][c] = acc[i][j] + bc[c];
        }
    __syncthreads();

    // per-row filter: max non-bg approx score vs PRE_TH
    if (tid < 64) {
        float m_all = sm.Ssc[tid][0];
        float m_fg = -INFINITY;
        for (int c = 1; c < CC_; ++c) {
            const float l = sm.Ssc[tid][c];
            m_all = fmaxf(m_all, l);
            m_fg = fmaxf(m_fg, l);
        }
        float denom = 0.f;
        for (int c = 0; c < CC_; ++c) denom += expf(sm.Ssc[tid][c] - m_all);
        const float maxsc = expf(m_fg - m_all) / denom;
        if (maxsc > PRE_TH) {
            const int pos = atomicAdd(nrowsp, 1);
            rowlist[pos] = row0 + tid;   // capacity 16000: cannot overflow
        }
    }
}

// ---------------------------------------------------------------------------
// Kernel 1b: fp64 logits GEMM on GATHERED rows (verbatim R6 math: same LDS
// layouts, same (double)a*(double)b strictly-sequential k order -> logits
// bit-identical to the passing R6 kernel). 32 gathered rows per block.
// ---------------------------------------------------------------------------
__global__ __launch_bounds__(256) void logits_fp64_rows(
    const float* __restrict__ A, const float* __restrict__ Wc,
    const float* __restrict__ bc,
    const int* __restrict__ rowlist, const int* __restrict__ nrowsp,
    float* __restrict__ cs, int* __restrict__ clab,
    int* __restrict__ corig, int* __restrict__ cpidx,
    int* __restrict__ cnt)
{
    const int nr = *nrowsp;
    const int row0 = blockIdx.x * 32;
    if (row0 >= nr) return;

    __shared__ union __align__(16) SM {
        struct { float Af[16][34]; float Bs[16][98]; } t;
        float Ssc[32][97];
    } sm;

    const int tid = threadIdx.x;
    const int ty2 = (tid >> 4) * 2;
    const int tx6 = (tid & 15) * 6;

    // A staging map (tid < 128): 32 gathered rows x 16 k via float4
    const int am = tid >> 2;         // row slot 0..31
    const int ak = (tid & 3) * 4;    // k subcol
    const float* Arow = nullptr;
    if (tid < 128) {
        const int ridx = min(row0 + am, nr - 1);   // duplicate tail (unused)
        Arow = A + (size_t)rowlist[ridx] * FF_;
    }
    // B staging map: 16 k x 96 cols, 6 scalars
    const int bk = tid >> 4;
    const int bn = (tid & 15) * 6;

    double acc[2][6];
#pragma unroll
    for (int i = 0; i < 2; ++i)
#pragma unroll
        for (int j = 0; j < 6; ++j) acc[i][j] = 0.0;

    // prologue prefetch (k0 = 0)
    float4 avP = make_float4(0.f, 0.f, 0.f, 0.f);
    if (tid < 128) avP = *reinterpret_cast<const float4*>(Arow + ak);
    float bvP[6];
#pragma unroll
    for (int jj = 0; jj < 6; ++jj) {
        const int c = bn + jj;
        bvP[jj] = (c < CC_) ? Wc[(size_t)bk * CC_ + c] : 0.f;
    }

    for (int k0 = 0; k0 < FF_; k0 += 16) {
        if (tid < 128) {
            sm.t.Af[ak + 0][am] = avP.x;
            sm.t.Af[ak + 1][am] = avP.y;
            sm.t.Af[ak + 2][am] = avP.z;
            sm.t.Af[ak + 3][am] = avP.w;
        }
#pragma unroll
        for (int jj = 0; jj < 6; ++jj) sm.t.Bs[bk][bn + jj] = bvP[jj];

        const int kn = k0 + 16;
        if (kn < FF_) {
            if (tid < 128)
                avP = *reinterpret_cast<const float4*>(Arow + kn + ak);
#pragma unroll
            for (int jj = 0; jj < 6; ++jj) {
                const int c = bn + jj;
                bvP[jj] = (c < CC_) ? Wc[(size_t)(kn + bk) * CC_ + c] : 0.f;
            }
        }
        __syncthreads();

#pragma unroll
        for (int k = 0; k < 16; ++k) {
            const float2 af = *reinterpret_cast<const float2*>(&sm.t.Af[k][ty2]);
            const float2 b01 = *reinterpret_cast<const float2*>(&sm.t.Bs[k][tx6 + 0]);
            const float2 b23 = *reinterpret_cast<const float2*>(&sm.t.Bs[k][tx6 + 2]);
            const float2 b45 = *reinterpret_cast<const float2*>(&sm.t.Bs[k][tx6 + 4]);
            const double a0 = (double)af.x, a1 = (double)af.y;
            const double b0 = (double)b01.x, b1 = (double)b01.y;
            const double b2 = (double)b23.x, b3 = (double)b23.y;
            const double b4 = (double)b45.x, b5 = (double)b45.y;
            acc[0][0] += a0 * b0; acc[0][1] += a0 * b1; acc[0][2] += a0 * b2;
            acc[0][3] += a0 * b3; acc[0][4] += a0 * b4; acc[0][5] += a0 * b5;
            acc[1][0] += a1 * b0; acc[1][1] += a1 * b1; acc[1][2] += a1 * b2;
            acc[1][3] += a1 * b3; acc[1][4] += a1 * b4; acc[1][5] += a1 * b5;
        }
        __syncthreads();
    }

    // fp32 logits (+bias) into overlay
#pragma unroll
    for (int i = 0; i < 2; ++i)
#pragma unroll
        for (int j = 0; j < 6; ++j) {
            const int c = tx6 + j;
            if (c < CC_) {
                const float lf = (float)acc[i][j];
                sm.Ssc[ty2 + i][c] = __fadd_rn(lf, bc[c]);
            }
        }
    __syncthreads();

    // per-row fp64 softmax + threshold; threads 0..31 (one gathered row each)
    if (tid < 32 && row0 + tid < nr) {
        const int p = rowlist[row0 + tid];
        const int b = p / PP_;
        const int pi = p - b * PP_;

        float m = sm.Ssc[tid][0];
        for (int c = 1; c < CC_; ++c) m = fmaxf(m, sm.Ssc[tid][c]);
        double denom = 0.0;
        for (int c = 0; c < CC_; ++c)
            denom += exp((double)sm.Ssc[tid][c] - (double)m);

        for (int c = 1; c < CC_; ++c) {
            const double sd = exp((double)sm.Ssc[tid][c] - (double)m) / denom;
            const float score = (float)sd;
            if (score > SCORE_TH) {
                const int pos = atomicAdd(&cnt[b], 1);
                if (pos < CAP_) {
                    const int g = b * CAP_ + pos;
                    cs[g] = score;
                    clab[g] = c;
                    corig[g] = pi * (CC_ - 1) + (c - 1);
                    cpidx[g] = p;
                }
            }
        }
    }
}

// ---------------------------------------------------------------------------
// Kernel 2: per-candidate box regression (FP64 dot) + strict-fp32 decode.
// (unchanged — bit-exact)
// ---------------------------------------------------------------------------
__global__ __launch_bounds__(256) void decode_cand(
    const float* __restrict__ A, const float* __restrict__ Wb,
    const float* __restrict__ bb, const float* __restrict__ props,
    const int* __restrict__ cnt, const int* __restrict__ clab,
    const int* __restrict__ cpidx,
    float* __restrict__ cs, float* __restrict__ cx1, float* __restrict__ cy1,
    float* __restrict__ cx2, float* __restrict__ cy2)
{
    const int wid = (blockIdx.x * 256 + threadIdx.x) >> 6;
    const int lane = threadIdx.x & 63;
    const int b = wid / CAP_;
    const int pos = wid - b * CAP_;
    if (b >= BB_) return;
    const int n = min(cnt[b], CAP_);
    if (pos >= n) return;

    const int g = b * CAP_ + pos;
    const int p = cpidx[g];
    const int c = clab[g];

    const float* fr = A + (size_t)p * FF_;
    const float* wb0 = Wb + 4 * c;

    double a0 = 0.0, a1 = 0.0, a2 = 0.0, a3 = 0.0;
    for (int k = lane; k < FF_; k += 64) {
        const double f = (double)fr[k];
        const float4 wv = *reinterpret_cast<const float4*>(wb0 + (size_t)k * (CC_ * 4));
        a0 += f * (double)wv.x; a1 += f * (double)wv.y;
        a2 += f * (double)wv.z; a3 += f * (double)wv.w;
    }
#pragma unroll
    for (int off = 32; off > 0; off >>= 1) {
        a0 += __shfl_xor(a0, off);
        a1 += __shfl_xor(a1, off);
        a2 += __shfl_xor(a2, off);
        a3 += __shfl_xor(a3, off);
    }

    if (lane == 0) {
        const float dx = __fadd_rn((float)a0, bb[4 * c + 0]);
        const float dy = __fadd_rn((float)a1, bb[4 * c + 1]);
        const float clipf = (float)BBOX_CLIP_D;
        const float dw = fminf(__fadd_rn((float)a2, bb[4 * c + 2]), clipf);
        const float dh = fminf(__fadd_rn((float)a3, bb[4 * c + 3]), clipf);

        const float px1 = props[(size_t)p * 4 + 0];
        const float py1 = props[(size_t)p * 4 + 1];
        const float px2 = props[(size_t)p * 4 + 2];
        const float py2 = props[(size_t)p * 4 + 3];
        const float w = __fsub_rn(px2, px1);
        const float h = __fsub_rn(py2, py1);
        const float cx = __fadd_rn(px1, __fmul_rn(0.5f, w));
        const float cy = __fadd_rn(py1, __fmul_rn(0.5f, h));

        const float pcx = __fadd_rn(__fmul_rn(dx, w), cx);
        const float pcy = __fadd_rn(__fmul_rn(dy, h), cy);
        const float ew = (float)exp((double)dw);
        const float eh = (float)exp((double)dh);
        const float pw = __fmul_rn(ew, w);
        const float ph = __fmul_rn(eh, h);

        const float hw = __fmul_rn(0.5f, pw);
        const float hh = __fmul_rn(0.5f, ph);
        const float bx1 = fminf(fmaxf(__fsub_rn(pcx, hw), 0.f), IMG_W);
        const float by1 = fminf(fmaxf(__fsub_rn(pcy, hh), 0.f), IMG_H);
        const float bx2 = fminf(fmaxf(__fadd_rn(pcx, hw), 0.f), IMG_W);
        const float by2 = fminf(fmaxf(__fadd_rn(pcy, hh), 0.f), IMG_H);

        cx1[g] = bx1; cy1[g] = by1; cx2[g] = bx2; cy2[g] = by2;
        if (!(__fsub_rn(bx2, bx1) >= MIN_SZ && __fsub_rn(by2, by1) >= MIN_SZ)) {
            cs[g] = -INFINITY;
        }
    }
}

// ---------------------------------------------------------------------------
// Kernel 3: per-(image,class) greedy NMS — one wave per (b,c) pair.
// (unchanged — bit-exact)
// ---------------------------------------------------------------------------
__global__ __launch_bounds__(64) void nms_class(
    const float* __restrict__ c_x1, const float* __restrict__ c_y1,
    const float* __restrict__ c_x2, const float* __restrict__ c_y2,
    const float* __restrict__ c_s, const int* __restrict__ c_lab,
    const int* __restrict__ c_orig, const int* __restrict__ cnt,
    ull* __restrict__ skey, float* __restrict__ sx1v, float* __restrict__ sy1v,
    float* __restrict__ sx2v, float* __restrict__ sy2v,
    int* __restrict__ slabv, int* __restrict__ scnt)
{
    const int blk = blockIdx.x;
    const int b = blk / (CC_ - 1);
    const int c = 1 + (blk - b * (CC_ - 1));
    const int lane = threadIdx.x;

    __shared__ ull kk[CLS_CAP];
    __shared__ float x1s[CLS_CAP], y1s[CLS_CAP], x2s[CLS_CAP], y2s[CLS_CAP];

    const int n = min(cnt[b], CAP_);

    int mcnt = 0;
    for (int i0 = 0; i0 < n; i0 += 64) {
        const int i = i0 + lane;
        bool take = false;
        float s = 0.f; int so = 0; int g = 0;
        if (i < n) {
            g = b * CAP_ + i;
            if (c_lab[g] == c) {
                s = c_s[g];
                if (s > 0.f) { take = true; so = c_orig[g]; }
            }
        }
        const ull bal = __ballot(take);
        if (take) {
            const int pos = mcnt + __popcll(bal & ((1ull << lane) - 1ull));
            if (pos < CLS_CAP) {
                kk[pos] = ((ull)__float_as_uint(s) << 32) |
                          (unsigned int)(0x7FFFFFFF - so);
                x1s[pos] = c_x1[g]; y1s[pos] = c_y1[g];
                x2s[pos] = c_x2[g]; y2s[pos] = c_y2[g];
            }
        }
        mcnt += (int)__popcll(bal);
    }
    mcnt = min(mcnt, CLS_CAP);
    if (mcnt == 0) return;
    __syncthreads();

    while (true) {
        ull best = 0ull;
        for (int i = lane; i < mcnt; i += 64) best = (kk[i] > best) ? kk[i] : best;
#pragma unroll
        for (int off = 32; off > 0; off >>= 1) {
            const ull o = __shfl_xor(best, off);
            best = (o > best) ? o : best;
        }
        if (best == 0ull) break;

        int wsl = -1;
        for (int i = lane; i < mcnt; i += 64) if (kk[i] == best) wsl = i;
        const ull bal = __ballot(wsl >= 0);
        const int wlane = (int)__ffsll((long long)bal) - 1;
        wsl = __shfl(wsl, wlane);

        const float wx1 = x1s[wsl], wy1 = y1s[wsl];
        const float wx2 = x2s[wsl], wy2 = y2s[wsl];

        if (lane == 0) {
            const int sp = atomicAdd(&scnt[b], 1);
            if (sp < SURV_CAP) {
                const int sg = b * SURV_CAP + sp;
                skey[sg] = best;
                sx1v[sg] = wx1; sy1v[sg] = wy1;
                sx2v[sg] = wx2; sy2v[sg] = wy2;
                slabv[sg] = c;
            }
        }

        const float off = __fmul_rn((float)c, OFF_);
        const float ax1 = __fadd_rn(wx1, off), ay1 = __fadd_rn(wy1, off);
        const float ax2 = __fadd_rn(wx2, off), ay2 = __fadd_rn(wy2, off);
        const float a1 = __fmul_rn(__fsub_rn(ax2, ax1), __fsub_rn(ay2, ay1));
        for (int i = lane; i < mcnt; i += 64) {
            if (kk[i] == 0ull) continue;
            const float bx1 = __fadd_rn(x1s[i], off), by1 = __fadd_rn(y1s[i], off);
            const float bx2 = __fadd_rn(x2s[i], off), by2 = __fadd_rn(y2s[i], off);
            const float ix1 = fmaxf(ax1, bx1), iy1 = fmaxf(ay1, by1);
            const float ix2 = fminf(ax2, bx2), iy2 = fminf(ay2, by2);
            const float inter = __fmul_rn(fmaxf(__fsub_rn(ix2, ix1), 0.f),
                                          fmaxf(__fsub_rn(iy2, iy1), 0.f));
            const float a2 = __fmul_rn(__fsub_rn(bx2, bx1), __fsub_rn(by2, by1));
            const float den = __fadd_rn(__fsub_rn(__fadd_rn(a1, a2), inter), 1e-9f);
            const float iou = __fdiv_rn(inter, den);
            if (iou > NMS_TH) kk[i] = 0ull;
        }
        __syncthreads();
    }
}

// ---------------------------------------------------------------------------
// Kernel 4: per-image merge — bitonic sort survivors by key (desc), emit
// top-100 in order. (unchanged — bit-exact)
// ---------------------------------------------------------------------------
__global__ __launch_bounds__(256) void nms_merge(
    const ull* __restrict__ skey, const float* __restrict__ sx1v,
    const float* __restrict__ sy1v, const float* __restrict__ sx2v,
    const float* __restrict__ sy2v, const int* __restrict__ slabv,
    const int* __restrict__ scnt, float* __restrict__ out)
{
    const int b = blockIdx.x;
    const int t = threadIdx.x;

    __shared__ ull k_[SURV_CAP];
    __shared__ int id_[SURV_CAP];

    const int m = min(scnt[b], SURV_CAP);
    int N2 = 128;
    while (N2 < m) N2 <<= 1;

    for (int i = t; i < N2; i += 256) {
        k_[i] = (i < m) ? skey[b * SURV_CAP + i] : 0ull;
        id_[i] = i;
    }
    __syncthreads();

    for (int ksz = 2; ksz <= N2; ksz <<= 1) {
        for (int j = ksz >> 1; j > 0; j >>= 1) {
            for (int i = t; i < N2; i += 256) {
                const int ixj = i ^ j;
                if (ixj > i) {
                    const ull a = k_[i], cc = k_[ixj];
                    const bool desc = ((i & ksz) == 0);
                    if (desc ? (a < cc) : (a > cc)) {
                        k_[i] = cc; k_[ixj] = a;
                        const int tmp = id_[i]; id_[i] = id_[ixj]; id_[ixj] = tmp;
                    }
                }
            }
            __syncthreads();
        }
    }

    const int boxes_base = 0;
    const int scores_base = BB_ * DETS_ * 4;
    const int labels_base = BB_ * DETS_ * 5;

    for (int r = t; r < DETS_; r += 256) {
        const ull key = (r < N2) ? k_[r] : 0ull;
        float* bo = out + boxes_base + (size_t)(b * DETS_ + r) * 4;
        if (key != 0ull) {
            const int sg = b * SURV_CAP + id_[r];
            bo[0] = sx1v[sg]; bo[1] = sy1v[sg];
            bo[2] = sx2v[sg]; bo[3] = sy2v[sg];
            out[scores_base + b * DETS_ + r] = __uint_as_float((unsigned)(key >> 32));
            out[labels_base + b * DETS_ + r] = (float)slabv[sg];
        } else {
            bo[0] = 0.f; bo[1] = 0.f; bo[2] = 0.f; bo[3] = 0.f;
            out[scores_base + b * DETS_ + r] = 0.f;
            out[labels_base + b * DETS_ + r] = 0.f;
        }
    }
}

// ---------------------------------------------------------------------------
extern "C" void kernel_launch(void* const* d_in, const int* in_sizes, int n_in,
                              void* d_out, int out_size, void* d_ws, size_t ws_size,
                              hipStream_t stream)
{
    const float* feat  = (const float*)d_in[0];
    const float* Wc    = (const float*)d_in[1];
    const float* bc    = (const float*)d_in[2];
    const float* Wb    = (const float*)d_in[3];
    const float* bb    = (const float*)d_in[4];
    const float* props = (const float*)d_in[5];
    for (int i = 0; i < n_in; ++i) {
        const float* q = (const float*)d_in[i];
        switch (in_sizes[i]) {
            case 16384000: feat  = q; break;  // [16000,1024]
            case 93184:    Wc    = q; break;  // [1024,91]
            case 91:       bc    = q; break;
            case 372736:   Wb    = q; break;  // [1024,364]
            case 364:      bb    = q; break;
            case 64000:    props = q; break;  // [16,1000,4]
        }
    }
    float* out = (float*)d_out;

    char* ws = (char*)d_ws;
    int*   cnt    = (int*)ws;            // 16 ints
    int*   scnt   = (int*)(ws + 64);     // 16 ints
    int*   nrowsp = (int*)(ws + 128);    // 1 int
    float* cs    = (float*)(ws + 256);
    int*   clab  = (int*)(cs + CAND_MAX);
    int*   corig = clab + CAND_MAX;
    int*   cpidx = corig + CAND_MAX;
    float* cx1   = (float*)(cpidx + CAND_MAX);
    float* cy1   = cx1 + CAND_MAX;
    float* cx2   = cy1 + CAND_MAX;
    float* cy2   = cx2 + CAND_MAX;
    ull*   skey  = (ull*)(cy2 + CAND_MAX);
    float* sx1v  = (float*)(skey + (size_t)BB_ * SURV_CAP);
    float* sy1v  = sx1v + (size_t)BB_ * SURV_CAP;
    float* sx2v  = sy1v + (size_t)BB_ * SURV_CAP;
    float* sy2v  = sx2v + (size_t)BB_ * SURV_CAP;
    int*   slabv = (int*)(sy2v + (size_t)BB_ * SURV_CAP);
    int*   rowlist = slabv + (size_t)BB_ * SURV_CAP;   // 16000 ints

    hipMemsetAsync(ws, 0, 256, stream);   // zero cnt + scnt + nrows

    prepass_rows<<<BB_ * PP_ / 64, 256, 0, stream>>>(feat, Wc, bc,
        rowlist, nrowsp);

    logits_fp64_rows<<<BB_ * PP_ / 32, 256, 0, stream>>>(feat, Wc, bc,
        rowlist, nrowsp, cs, clab, corig, cpidx, cnt);

    decode_cand<<<CAND_MAX / 4, 256, 0, stream>>>(feat, Wb, bb, props,
        cnt, clab, cpidx, cs, cx1, cy1, cx2, cy2);

    nms_class<<<BB_ * (CC_ - 1), 64, 0, stream>>>(
        cx1, cy1, cx2, cy2, cs, clab, corig, cnt,
        skey, sx1v, sy1v, sx2v, sy2v, slabv, scnt);

    nms_merge<<<BB_, 256, 0, stream>>>(
        skey, sx1v, sy1v, sx2v, sy2v, slabv, scnt, out);
}

// Round 12
// 325.251 us; speedup vs baseline: 1.0674x; 1.0674x over previous
//
#include <hip/hip_runtime.h>
#include <hip/hip_bf16.h>
#include <math.h>

typedef unsigned long long ull;

// Problem constants
#define BB_ 16          // images
#define PP_ 1000        // proposals per image
#define CC_ 91          // classes incl background
#define FF_ 1024        // feature dim
#define DETS_ 100
#define CAP_ 2048       // candidate capacity per image (measured ~320)
#define CAND_MAX (BB_ * CAP_)
#define SURV_CAP 2048   // NMS-survivor capacity per image
#define CLS_CAP 256     // per-(image,class) candidate capacity
#define IMG_W 800.0f
#define IMG_H 800.0f
#define OFF_ 802.0f     // max(H,W)+2
#define SCORE_TH 0.05f
#define PRE_TH 0.047f   // prepass cutoff: 3e-3 margin >> 1e-5 fp32 error bound
#define NMS_TH 0.5f
#define MIN_SZ 0.01f
#define BBOX_CLIP_D 4.135166556742356   // log(1000/16)

// ---------------------------------------------------------------------------
// Kernel 1a: fp32 prepass — 32 rows x 91 cols per block, 500 blocks
// (2 blocks/CU). R6 skeleton with fp32 accumulators (12 FMA/thread/k-step).
// Emits rows whose approx max fg score > PRE_TH into rowlist.
// ---------------------------------------------------------------------------
__global__ __launch_bounds__(256) void prepass_rows(
    const float* __restrict__ A, const float* __restrict__ Wc,
    const float* __restrict__ bc,
    int* __restrict__ rowlist, int* __restrict__ nrowsp)
{
    __shared__ union __align__(16) SM {
        struct { float Af[16][34]; float Bs[16][98]; } t;   // 8.4 KB
        float Ssc[32][97];                                  // 12.4 KB overlay
    } sm;

    const int tid = threadIdx.x;
    const int row0 = blockIdx.x * 32;
    const int ty2 = (tid >> 4) * 2;
    const int tx6 = (tid & 15) * 6;

    // A staging (tid < 128): 32 rows x 16 k via float4
    const int am = tid >> 2;
    const int ak = (tid & 3) * 4;
    // B staging (all 256): 16 k x 96 cols, 6 scalars
    const int bk = tid >> 4;
    const int bn = (tid & 15) * 6;

    float acc[2][6];
#pragma unroll
    for (int i = 0; i < 2; ++i)
#pragma unroll
        for (int j = 0; j < 6; ++j) acc[i][j] = 0.f;

    float4 avP = make_float4(0.f, 0.f, 0.f, 0.f);
    if (tid < 128)
        avP = *reinterpret_cast<const float4*>(A + (size_t)(row0 + am) * FF_ + ak);
    float bvP[6];
#pragma unroll
    for (int jj = 0; jj < 6; ++jj) {
        const int c = bn + jj;
        bvP[jj] = (c < CC_) ? Wc[(size_t)bk * CC_ + c] : 0.f;
    }

    for (int k0 = 0; k0 < FF_; k0 += 16) {
        if (tid < 128) {
            sm.t.Af[ak + 0][am] = avP.x;
            sm.t.Af[ak + 1][am] = avP.y;
            sm.t.Af[ak + 2][am] = avP.z;
            sm.t.Af[ak + 3][am] = avP.w;
        }
#pragma unroll
        for (int jj = 0; jj < 6; ++jj) sm.t.Bs[bk][bn + jj] = bvP[jj];

        const int kn = k0 + 16;
        if (kn < FF_) {
            if (tid < 128)
                avP = *reinterpret_cast<const float4*>(
                    A + (size_t)(row0 + am) * FF_ + kn + ak);
#pragma unroll
            for (int jj = 0; jj < 6; ++jj) {
                const int c = bn + jj;
                bvP[jj] = (c < CC_) ? Wc[(size_t)(kn + bk) * CC_ + c] : 0.f;
            }
        }
        __syncthreads();

#pragma unroll
        for (int k = 0; k < 16; ++k) {
            const float2 af = *reinterpret_cast<const float2*>(&sm.t.Af[k][ty2]);
            const float2 b01 = *reinterpret_cast<const float2*>(&sm.t.Bs[k][tx6 + 0]);
            const float2 b23 = *reinterpret_cast<const float2*>(&sm.t.Bs[k][tx6 + 2]);
            const float2 b45 = *reinterpret_cast<const float2*>(&sm.t.Bs[k][tx6 + 4]);
            const float a0 = af.x, a1 = af.y;
            acc[0][0] += a0 * b01.x; acc[0][1] += a0 * b01.y;
            acc[0][2] += a0 * b23.x; acc[0][3] += a0 * b23.y;
            acc[0][4] += a0 * b45.x; acc[0][5] += a0 * b45.y;
            acc[1][0] += a1 * b01.x; acc[1][1] += a1 * b01.y;
            acc[1][2] += a1 * b23.x; acc[1][3] += a1 * b23.y;
            acc[1][4] += a1 * b45.x; acc[1][5] += a1 * b45.y;
        }
        __syncthreads();
    }

#pragma unroll
    for (int i = 0; i < 2; ++i)
#pragma unroll
        for (int j = 0; j < 6; ++j) {
            const int c = tx6 + j;
            if (c < CC_) sm.Ssc[ty2 + i][c] = acc[i][j] + bc[c];
        }
    __syncthreads();

    if (tid < 32) {
        float m_all = sm.Ssc[tid][0];
        float m_fg = -INFINITY;
        for (int c = 1; c < CC_; ++c) {
            const float l = sm.Ssc[tid][c];
            m_all = fmaxf(m_all, l);
            m_fg = fmaxf(m_fg, l);
        }
        float denom = 0.f;
        for (int c = 0; c < CC_; ++c) denom += expf(sm.Ssc[tid][c] - m_all);
        const float maxsc = expf(m_fg - m_all) / denom;
        if (maxsc > PRE_TH) {
            const int pos = atomicAdd(nrowsp, 1);
            rowlist[pos] = row0 + tid;   // capacity 16000: cannot overflow
        }
    }
}

// ---------------------------------------------------------------------------
// Kernel 1b: fp64 logits on GATHERED rows. 512 threads (8 waves), in-block
// split-K=2: waves 0-3 accumulate k=0..511, waves 4-7 k=512..1023 (each with
// R6's verbatim tile layout/inner loop), fixed-order combine lo+hi via LDS.
// fp64-accurate scores (~1e-15 rel) -> identical fp32 score bits in practice.
// ---------------------------------------------------------------------------
__global__ __launch_bounds__(512) void logits_fp64_rows(
    const float* __restrict__ A, const float* __restrict__ Wc,
    const float* __restrict__ bc,
    const int* __restrict__ rowlist, const int* __restrict__ nrowsp,
    float* __restrict__ cs, int* __restrict__ clab,
    int* __restrict__ corig, int* __restrict__ cpidx,
    int* __restrict__ cnt)
{
    const int nr = *nrowsp;
    const int row0 = blockIdx.x * 32;
    if (row0 >= nr) return;

    __shared__ __align__(16) float Af[2][16][34];   // 4.3 KB
    __shared__ __align__(16) float Bs[2][16][98];   // 12.5 KB
    __shared__ __align__(16) double comb[256][12];  // 24.6 KB
    __shared__ float Ssc[32][97];                   // 12.4 KB

    const int tid = threadIdx.x;
    const int kg = tid >> 8;           // k-group 0 (lo) / 1 (hi)
    const int l = tid & 255;
    const int ty2 = (l >> 4) * 2;
    const int tx6 = (l & 15) * 6;
    const int kbase = kg * 512;

    // A staging (l < 128): 32 gathered rows x 16 k via float4
    const int am = l >> 2;
    const int ak = (l & 3) * 4;
    const float* Arow = nullptr;
    if (l < 128) {
        const int ridx = min(row0 + am, nr - 1);   // clamped tail (unused)
        Arow = A + (size_t)rowlist[ridx] * FF_ + kbase;
    }
    // B staging (all 256 of group): 16 k x 96 cols, 6 scalars
    const int bk = l >> 4;
    const int bn = (l & 15) * 6;

    double acc[2][6];
#pragma unroll
    for (int i = 0; i < 2; ++i)
#pragma unroll
        for (int j = 0; j < 6; ++j) acc[i][j] = 0.0;

    float4 avP = make_float4(0.f, 0.f, 0.f, 0.f);
    if (l < 128) avP = *reinterpret_cast<const float4*>(Arow + ak);
    float bvP[6];
#pragma unroll
    for (int jj = 0; jj < 6; ++jj) {
        const int c = bn + jj;
        bvP[jj] = (c < CC_) ? Wc[(size_t)(kbase + bk) * CC_ + c] : 0.f;
    }

    for (int k0 = 0; k0 < 512; k0 += 16) {
        if (l < 128) {
            Af[kg][ak + 0][am] = avP.x;
            Af[kg][ak + 1][am] = avP.y;
            Af[kg][ak + 2][am] = avP.z;
            Af[kg][ak + 3][am] = avP.w;
        }
#pragma unroll
        for (int jj = 0; jj < 6; ++jj) Bs[kg][bk][bn + jj] = bvP[jj];

        const int kn = k0 + 16;
        if (kn < 512) {
            if (l < 128)
                avP = *reinterpret_cast<const float4*>(Arow + kn + ak);
#pragma unroll
            for (int jj = 0; jj < 6; ++jj) {
                const int c = bn + jj;
                bvP[jj] = (c < CC_) ? Wc[(size_t)(kbase + kn + bk) * CC_ + c] : 0.f;
            }
        }
        __syncthreads();

#pragma unroll
        for (int k = 0; k < 16; ++k) {
            const float2 af = *reinterpret_cast<const float2*>(&Af[kg][k][ty2]);
            const float2 b01 = *reinterpret_cast<const float2*>(&Bs[kg][k][tx6 + 0]);
            const float2 b23 = *reinterpret_cast<const float2*>(&Bs[kg][k][tx6 + 2]);
            const float2 b45 = *reinterpret_cast<const float2*>(&Bs[kg][k][tx6 + 4]);
            const double a0 = (double)af.x, a1 = (double)af.y;
            const double b0 = (double)b01.x, b1 = (double)b01.y;
            const double b2 = (double)b23.x, b3 = (double)b23.y;
            const double b4 = (double)b45.x, b5 = (double)b45.y;
            acc[0][0] += a0 * b0; acc[0][1] += a0 * b1; acc[0][2] += a0 * b2;
            acc[0][3] += a0 * b3; acc[0][4] += a0 * b4; acc[0][5] += a0 * b5;
            acc[1][0] += a1 * b0; acc[1][1] += a1 * b1; acc[1][2] += a1 * b2;
            acc[1][3] += a1 * b3; acc[1][4] += a1 * b4; acc[1][5] += a1 * b5;
        }
        __syncthreads();
    }

    // fixed-order combine: lo + hi
    if (kg == 1) {
#pragma unroll
        for (int i = 0; i < 2; ++i)
#pragma unroll
            for (int j = 0; j < 6; ++j) comb[l][i * 6 + j] = acc[i][j];
    }
    __syncthreads();
    if (kg == 0) {
#pragma unroll
        for (int i = 0; i < 2; ++i)
#pragma unroll
            for (int j = 0; j < 6; ++j) {
                const int c = tx6 + j;
                if (c < CC_) {
                    const double v = acc[i][j] + comb[l][i * 6 + j];
                    Ssc[ty2 + i][c] = __fadd_rn((float)v, bc[c]);
                }
            }
    }
    __syncthreads();

    // per-row fp64 softmax + threshold; threads 0..31 (one gathered row each)
    if (tid < 32 && row0 + tid < nr) {
        const int p = rowlist[row0 + tid];
        const int b = p / PP_;
        const int pi = p - b * PP_;

        float m = Ssc[tid][0];
        for (int c = 1; c < CC_; ++c) m = fmaxf(m, Ssc[tid][c]);
        double denom = 0.0;
        for (int c = 0; c < CC_; ++c)
            denom += exp((double)Ssc[tid][c] - (double)m);

        for (int c = 1; c < CC_; ++c) {
            const double sd = exp((double)Ssc[tid][c] - (double)m) / denom;
            const float score = (float)sd;
            if (score > SCORE_TH) {
                const int pos = atomicAdd(&cnt[b], 1);
                if (pos < CAP_) {
                    const int g = b * CAP_ + pos;
                    cs[g] = score;
                    clab[g] = c;
                    corig[g] = pi * (CC_ - 1) + (c - 1);
                    cpidx[g] = p;
                }
            }
        }
    }
}

// ---------------------------------------------------------------------------
// Kernel 2: per-candidate box regression (FP64 dot) + strict-fp32 decode.
// (unchanged — bit-exact)
// ---------------------------------------------------------------------------
__global__ __launch_bounds__(256) void decode_cand(
    const float* __restrict__ A, const float* __restrict__ Wb,
    const float* __restrict__ bb, const float* __restrict__ props,
    const int* __restrict__ cnt, const int* __restrict__ clab,
    const int* __restrict__ cpidx,
    float* __restrict__ cs, float* __restrict__ cx1, float* __restrict__ cy1,
    float* __restrict__ cx2, float* __restrict__ cy2)
{
    const int wid = (blockIdx.x * 256 + threadIdx.x) >> 6;
    const int lane = threadIdx.x & 63;
    const int b = wid / CAP_;
    const int pos = wid - b * CAP_;
    if (b >= BB_) return;
    const int n = min(cnt[b], CAP_);
    if (pos >= n) return;

    const int g = b * CAP_ + pos;
    const int p = cpidx[g];
    const int c = clab[g];

    const float* fr = A + (size_t)p * FF_;
    const float* wb0 = Wb + 4 * c;

    double a0 = 0.0, a1 = 0.0, a2 = 0.0, a3 = 0.0;
    for (int k = lane; k < FF_; k += 64) {
        const double f = (double)fr[k];
        const float4 wv = *reinterpret_cast<const float4*>(wb0 + (size_t)k * (CC_ * 4));
        a0 += f * (double)wv.x; a1 += f * (double)wv.y;
        a2 += f * (double)wv.z; a3 += f * (double)wv.w;
    }
#pragma unroll
    for (int off = 32; off > 0; off >>= 1) {
        a0 += __shfl_xor(a0, off);
        a1 += __shfl_xor(a1, off);
        a2 += __shfl_xor(a2, off);
        a3 += __shfl_xor(a3, off);
    }

    if (lane == 0) {
        const float dx = __fadd_rn((float)a0, bb[4 * c + 0]);
        const float dy = __fadd_rn((float)a1, bb[4 * c + 1]);
        const float clipf = (float)BBOX_CLIP_D;
        const float dw = fminf(__fadd_rn((float)a2, bb[4 * c + 2]), clipf);
        const float dh = fminf(__fadd_rn((float)a3, bb[4 * c + 3]), clipf);

        const float px1 = props[(size_t)p * 4 + 0];
        const float py1 = props[(size_t)p * 4 + 1];
        const float px2 = props[(size_t)p * 4 + 2];
        const float py2 = props[(size_t)p * 4 + 3];
        const float w = __fsub_rn(px2, px1);
        const float h = __fsub_rn(py2, py1);
        const float cx = __fadd_rn(px1, __fmul_rn(0.5f, w));
        const float cy = __fadd_rn(py1, __fmul_rn(0.5f, h));

        const float pcx = __fadd_rn(__fmul_rn(dx, w), cx);
        const float pcy = __fadd_rn(__fmul_rn(dy, h), cy);
        const float ew = (float)exp((double)dw);
        const float eh = (float)exp((double)dh);
        const float pw = __fmul_rn(ew, w);
        const float ph = __fmul_rn(eh, h);

        const float hw = __fmul_rn(0.5f, pw);
        const float hh = __fmul_rn(0.5f, ph);
        const float bx1 = fminf(fmaxf(__fsub_rn(pcx, hw), 0.f), IMG_W);
        const float by1 = fminf(fmaxf(__fsub_rn(pcy, hh), 0.f), IMG_H);
        const float bx2 = fminf(fmaxf(__fadd_rn(pcx, hw), 0.f), IMG_W);
        const float by2 = fminf(fmaxf(__fadd_rn(pcy, hh), 0.f), IMG_H);

        cx1[g] = bx1; cy1[g] = by1; cx2[g] = bx2; cy2[g] = by2;
        if (!(__fsub_rn(bx2, bx1) >= MIN_SZ && __fsub_rn(by2, by1) >= MIN_SZ)) {
            cs[g] = -INFINITY;
        }
    }
}

// ---------------------------------------------------------------------------
// Kernel 3: per-(image,class) greedy NMS — one wave per (b,c) pair.
// (unchanged — bit-exact)
// ---------------------------------------------------------------------------
__global__ __launch_bounds__(64) void nms_class(
    const float* __restrict__ c_x1, const float* __restrict__ c_y1,
    const float* __restrict__ c_x2, const float* __restrict__ c_y2,
    const float* __restrict__ c_s, const int* __restrict__ c_lab,
    const int* __restrict__ c_orig, const int* __restrict__ cnt,
    ull* __restrict__ skey, float* __restrict__ sx1v, float* __restrict__ sy1v,
    float* __restrict__ sx2v, float* __restrict__ sy2v,
    int* __restrict__ slabv, int* __restrict__ scnt)
{
    const int blk = blockIdx.x;
    const int b = blk / (CC_ - 1);
    const int c = 1 + (blk - b * (CC_ - 1));
    const int lane = threadIdx.x;

    __shared__ ull kk[CLS_CAP];
    __shared__ float x1s[CLS_CAP], y1s[CLS_CAP], x2s[CLS_CAP], y2s[CLS_CAP];

    const int n = min(cnt[b], CAP_);

    int mcnt = 0;
    for (int i0 = 0; i0 < n; i0 += 64) {
        const int i = i0 + lane;
        bool take = false;
        float s = 0.f; int so = 0; int g = 0;
        if (i < n) {
            g = b * CAP_ + i;
            if (c_lab[g] == c) {
                s = c_s[g];
                if (s > 0.f) { take = true; so = c_orig[g]; }
            }
        }
        const ull bal = __ballot(take);
        if (take) {
            const int pos = mcnt + __popcll(bal & ((1ull << lane) - 1ull));
            if (pos < CLS_CAP) {
                kk[pos] = ((ull)__float_as_uint(s) << 32) |
                          (unsigned int)(0x7FFFFFFF - so);
                x1s[pos] = c_x1[g]; y1s[pos] = c_y1[g];
                x2s[pos] = c_x2[g]; y2s[pos] = c_y2[g];
            }
        }
        mcnt += (int)__popcll(bal);
    }
    mcnt = min(mcnt, CLS_CAP);
    if (mcnt == 0) return;
    __syncthreads();

    while (true) {
        ull best = 0ull;
        for (int i = lane; i < mcnt; i += 64) best = (kk[i] > best) ? kk[i] : best;
#pragma unroll
        for (int off = 32; off > 0; off >>= 1) {
            const ull o = __shfl_xor(best, off);
            best = (o > best) ? o : best;
        }
        if (best == 0ull) break;

        int wsl = -1;
        for (int i = lane; i < mcnt; i += 64) if (kk[i] == best) wsl = i;
        const ull bal = __ballot(wsl >= 0);
        const int wlane = (int)__ffsll((long long)bal) - 1;
        wsl = __shfl(wsl, wlane);

        const float wx1 = x1s[wsl], wy1 = y1s[wsl];
        const float wx2 = x2s[wsl], wy2 = y2s[wsl];

        if (lane == 0) {
            const int sp = atomicAdd(&scnt[b], 1);
            if (sp < SURV_CAP) {
                const int sg = b * SURV_CAP + sp;
                skey[sg] = best;
                sx1v[sg] = wx1; sy1v[sg] = wy1;
                sx2v[sg] = wx2; sy2v[sg] = wy2;
                slabv[sg] = c;
            }
        }

        const float off = __fmul_rn((float)c, OFF_);
        const float ax1 = __fadd_rn(wx1, off), ay1 = __fadd_rn(wy1, off);
        const float ax2 = __fadd_rn(wx2, off), ay2 = __fadd_rn(wy2, off);
        const float a1 = __fmul_rn(__fsub_rn(ax2, ax1), __fsub_rn(ay2, ay1));
        for (int i = lane; i < mcnt; i += 64) {
            if (kk[i] == 0ull) continue;
            const float bx1 = __fadd_rn(x1s[i], off), by1 = __fadd_rn(y1s[i], off);
            const float bx2 = __fadd_rn(x2s[i], off), by2 = __fadd_rn(y2s[i], off);
            const float ix1 = fmaxf(ax1, bx1), iy1 = fmaxf(ay1, by1);
            const float ix2 = fminf(ax2, bx2), iy2 = fminf(ay2, by2);
            const float inter = __fmul_rn(fmaxf(__fsub_rn(ix2, ix1), 0.f),
                                          fmaxf(__fsub_rn(iy2, iy1), 0.f));
            const float a2 = __fmul_rn(__fsub_rn(bx2, bx1), __fsub_rn(by2, by1));
            const float den = __fadd_rn(__fsub_rn(__fadd_rn(a1, a2), inter), 1e-9f);
            const float iou = __fdiv_rn(inter, den);
            if (iou > NMS_TH) kk[i] = 0ull;
        }
        __syncthreads();
    }
}

// ---------------------------------------------------------------------------
// Kernel 4: per-image merge — bitonic sort survivors by key (desc), emit
// top-100 in order. (unchanged — bit-exact)
// ---------------------------------------------------------------------------
__global__ __launch_bounds__(256) void nms_merge(
    const ull* __restrict__ skey, const float* __restrict__ sx1v,
    const float* __restrict__ sy1v, const float* __restrict__ sx2v,
    const float* __restrict__ sy2v, const int* __restrict__ slabv,
    const int* __restrict__ scnt, float* __restrict__ out)
{
    const int b = blockIdx.x;
    const int t = threadIdx.x;

    __shared__ ull k_[SURV_CAP];
    __shared__ int id_[SURV_CAP];

    const int m = min(scnt[b], SURV_CAP);
    int N2 = 128;
    while (N2 < m) N2 <<= 1;

    for (int i = t; i < N2; i += 256) {
        k_[i] = (i < m) ? skey[b * SURV_CAP + i] : 0ull;
        id_[i] = i;
    }
    __syncthreads();

    for (int ksz = 2; ksz <= N2; ksz <<= 1) {
        for (int j = ksz >> 1; j > 0; j >>= 1) {
            for (int i = t; i < N2; i += 256) {
                const int ixj = i ^ j;
                if (ixj > i) {
                    const ull a = k_[i], cc = k_[ixj];
                    const bool desc = ((i & ksz) == 0);
                    if (desc ? (a < cc) : (a > cc)) {
                        k_[i] = cc; k_[ixj] = a;
                        const int tmp = id_[i]; id_[i] = id_[ixj]; id_[ixj] = tmp;
                    }
                }
            }
            __syncthreads();
        }
    }

    const int boxes_base = 0;
    const int scores_base = BB_ * DETS_ * 4;
    const int labels_base = BB_ * DETS_ * 5;

    for (int r = t; r < DETS_; r += 256) {
        const ull key = (r < N2) ? k_[r] : 0ull;
        float* bo = out + boxes_base + (size_t)(b * DETS_ + r) * 4;
        if (key != 0ull) {
            const int sg = b * SURV_CAP + id_[r];
            bo[0] = sx1v[sg]; bo[1] = sy1v[sg];
            bo[2] = sx2v[sg]; bo[3] = sy2v[sg];
            out[scores_base + b * DETS_ + r] = __uint_as_float((unsigned)(key >> 32));
            out[labels_base + b * DETS_ + r] = (float)slabv[sg];
        } else {
            bo[0] = 0.f; bo[1] = 0.f; bo[2] = 0.f; bo[3] = 0.f;
            out[scores_base + b * DETS_ + r] = 0.f;
            out[labels_base + b * DETS_ + r] = 0.f;
        }
    }
}

// ---------------------------------------------------------------------------
extern "C" void kernel_launch(void* const* d_in, const int* in_sizes, int n_in,
                              void* d_out, int out_size, void* d_ws, size_t ws_size,
                              hipStream_t stream)
{
    const float* feat  = (const float*)d_in[0];
    const float* Wc    = (const float*)d_in[1];
    const float* bc    = (const float*)d_in[2];
    const float* Wb    = (const float*)d_in[3];
    const float* bb    = (const float*)d_in[4];
    const float* props = (const float*)d_in[5];
    for (int i = 0; i < n_in; ++i) {
        const float* q = (const float*)d_in[i];
        switch (in_sizes[i]) {
            case 16384000: feat  = q; break;  // [16000,1024]
            case 93184:    Wc    = q; break;  // [1024,91]
            case 91:       bc    = q; break;
            case 372736:   Wb    = q; break;  // [1024,364]
            case 364:      bb    = q; break;
            case 64000:    props = q; break;  // [16,1000,4]
        }
    }
    float* out = (float*)d_out;

    char* ws = (char*)d_ws;
    int*   cnt    = (int*)ws;            // 16 ints
    int*   scnt   = (int*)(ws + 64);     // 16 ints
    int*   nrowsp = (int*)(ws + 128);    // 1 int
    float* cs    = (float*)(ws + 256);
    int*   clab  = (int*)(cs + CAND_MAX);
    int*   corig = clab + CAND_MAX;
    int*   cpidx = corig + CAND_MAX;
    float* cx1   = (float*)(cpidx + CAND_MAX);
    float* cy1   = cx1 + CAND_MAX;
    float* cx2   = cy1 + CAND_MAX;
    float* cy2   = cx2 + CAND_MAX;
    ull*   skey  = (ull*)(cy2 + CAND_MAX);
    float* sx1v  = (float*)(skey + (size_t)BB_ * SURV_CAP);
    float* sy1v  = sx1v + (size_t)BB_ * SURV_CAP;
    float* sx2v  = sy1v + (size_t)BB_ * SURV_CAP;
    float* sy2v  = sx2v + (size_t)BB_ * SURV_CAP;
    int*   slabv = (int*)(sy2v + (size_t)BB_ * SURV_CAP);
    int*   rowlist = slabv + (size_t)BB_ * SURV_CAP;   // 16000 ints

    hipMemsetAsync(ws, 0, 256, stream);   // zero cnt + scnt + nrows

    prepass_rows<<<BB_ * PP_ / 32, 256, 0, stream>>>(feat, Wc, bc,
        rowlist, nrowsp);

    logits_fp64_rows<<<BB_ * PP_ / 32, 512, 0, stream>>>(feat, Wc, bc,
        rowlist, nrowsp, cs, clab, corig, cpidx, cnt);

    decode_cand<<<CAND_MAX / 4, 256, 0, stream>>>(feat, Wb, bb, props,
        cnt, clab, cpidx, cs, cx1, cy1, cx2, cy2);

    nms_class<<<BB_ * (CC_ - 1), 64, 0, stream>>>(
        cx1, cy1, cx2, cy2, cs, clab, corig, cnt,
        skey, sx1v, sy1v, sx2v, sy2v, slabv, scnt);

    nms_merge<<<BB_, 256, 0, stream>>>(
        skey, sx1v, sy1v, sx2v, sy2v, slabv, scnt, out);
}

// Round 13
// 288.462 us; speedup vs baseline: 1.2035x; 1.1275x over previous
//
#include <hip/hip_runtime.h>
#include <hip/hip_bf16.h>
#include <math.h>

typedef unsigned long long ull;

// Problem constants
#define BB_ 16          // images
#define PP_ 1000        // proposals per image
#define CC_ 91          // classes incl background
#define FF_ 1024        // feature dim
#define DETS_ 100
#define CAP_ 2048       // candidate capacity per image (measured ~320)
#define CAND_MAX (BB_ * CAP_)
#define SURV_CAP 2048   // NMS-survivor capacity per image
#define CLS_CAP 256     // per-(image,class) candidate capacity
#define IMG_W 800.0f
#define IMG_H 800.0f
#define OFF_ 802.0f     // max(H,W)+2
#define SCORE_TH 0.05f
#define PRE_TH 0.047f   // prepass cutoff: 3e-3 margin >> 1e-5 fp32 error bound
#define NMS_TH 0.5f
#define MIN_SZ 0.01f
#define BBOX_CLIP_D 4.135166556742356   // log(1000/16)

// ---------------------------------------------------------------------------
// Kernel 0: Wb [1024][364] -> Wbt [91][4][1024] (exact copy, coalesced decode)
// ---------------------------------------------------------------------------
__global__ __launch_bounds__(256) void wb_transpose(
    const float* __restrict__ Wb, float* __restrict__ Wbt)
{
    const int idx = blockIdx.x * 256 + threadIdx.x;
    if (idx >= CC_ * 4 * FF_) return;
    const int c = idx >> 12;            // /4096
    const int j = (idx >> 10) & 3;
    const int k = idx & 1023;
    if (c < 1) { Wbt[idx] = 0.f; return; }     // class 0 never used
    Wbt[idx] = Wb[(size_t)k * (CC_ * 4) + 4 * c + j];
}

// ---------------------------------------------------------------------------
// Kernel 1a: fp32 prepass — 32 rows x 91 cols, 500 blocks, 512 threads,
// split-K=2. Emits rows with approx max fg score > PRE_TH.
// ---------------------------------------------------------------------------
__global__ __launch_bounds__(512) void prepass_rows(
    const float* __restrict__ A, const float* __restrict__ Wc,
    const float* __restrict__ bc,
    int* __restrict__ rowlist, int* __restrict__ nrowsp)
{
    __shared__ union __align__(16) SM {
        struct { float Af[2][16][34]; float Bs[2][16][98]; } t;  // 16.9 KB
        float Ssc[32][97];                                       // overlay
    } sm;
    __shared__ float comb[256][12];                              // 12.3 KB

    const int tid = threadIdx.x;
    const int kg = tid >> 8;            // k-group 0/1
    const int l = tid & 255;
    const int row0 = blockIdx.x * 32;
    const int kbase = kg * 512;
    const int ty2 = (l >> 4) * 2;
    const int tx6 = (l & 15) * 6;

    const int am = l >> 2;
    const int ak = (l & 3) * 4;
    const int bk = l >> 4;
    const int bn = (l & 15) * 6;

    float acc[2][6];
#pragma unroll
    for (int i = 0; i < 2; ++i)
#pragma unroll
        for (int j = 0; j < 6; ++j) acc[i][j] = 0.f;

    float4 avP = make_float4(0.f, 0.f, 0.f, 0.f);
    if (l < 128)
        avP = *reinterpret_cast<const float4*>(
            A + (size_t)(row0 + am) * FF_ + kbase + ak);
    float bvP[6];
#pragma unroll
    for (int jj = 0; jj < 6; ++jj) {
        const int c = bn + jj;
        bvP[jj] = (c < CC_) ? Wc[(size_t)(kbase + bk) * CC_ + c] : 0.f;
    }

    for (int k0 = 0; k0 < 512; k0 += 16) {
        if (l < 128) {
            sm.t.Af[kg][ak + 0][am] = avP.x;
            sm.t.Af[kg][ak + 1][am] = avP.y;
            sm.t.Af[kg][ak + 2][am] = avP.z;
            sm.t.Af[kg][ak + 3][am] = avP.w;
        }
#pragma unroll
        for (int jj = 0; jj < 6; ++jj) sm.t.Bs[kg][bk][bn + jj] = bvP[jj];

        const int kn = k0 + 16;
        if (kn < 512) {
            if (l < 128)
                avP = *reinterpret_cast<const float4*>(
                    A + (size_t)(row0 + am) * FF_ + kbase + kn + ak);
#pragma unroll
            for (int jj = 0; jj < 6; ++jj) {
                const int c = bn + jj;
                bvP[jj] = (c < CC_) ? Wc[(size_t)(kbase + kn + bk) * CC_ + c] : 0.f;
            }
        }
        __syncthreads();

#pragma unroll
        for (int k = 0; k < 16; ++k) {
            const float2 af = *reinterpret_cast<const float2*>(&sm.t.Af[kg][k][ty2]);
            const float2 b01 = *reinterpret_cast<const float2*>(&sm.t.Bs[kg][k][tx6 + 0]);
            const float2 b23 = *reinterpret_cast<const float2*>(&sm.t.Bs[kg][k][tx6 + 2]);
            const float2 b45 = *reinterpret_cast<const float2*>(&sm.t.Bs[kg][k][tx6 + 4]);
            const float a0 = af.x, a1 = af.y;
            acc[0][0] += a0 * b01.x; acc[0][1] += a0 * b01.y;
            acc[0][2] += a0 * b23.x; acc[0][3] += a0 * b23.y;
            acc[0][4] += a0 * b45.x; acc[0][5] += a0 * b45.y;
            acc[1][0] += a1 * b01.x; acc[1][1] += a1 * b01.y;
            acc[1][2] += a1 * b23.x; acc[1][3] += a1 * b23.y;
            acc[1][4] += a1 * b45.x; acc[1][5] += a1 * b45.y;
        }
        __syncthreads();
    }

    // combine lo+hi (fp32, prepass is approximate)
    if (kg == 1) {
#pragma unroll
        for (int i = 0; i < 2; ++i)
#pragma unroll
            for (int j = 0; j < 6; ++j) comb[l][i * 6 + j] = acc[i][j];
    }
    __syncthreads();
    if (kg == 0) {
#pragma unroll
        for (int i = 0; i < 2; ++i)
#pragma unroll
            for (int j = 0; j < 6; ++j) {
                const int c = tx6 + j;
                if (c < CC_)
                    sm.Ssc[ty2 + i][c] = acc[i][j] + comb[l][i * 6 + j] + bc[c];
            }
    }
    __syncthreads();

    if (tid < 32) {
        float m_all = sm.Ssc[tid][0];
        float m_fg = -INFINITY;
        for (int c = 1; c < CC_; ++c) {
            const float lv = sm.Ssc[tid][c];
            m_all = fmaxf(m_all, lv);
            m_fg = fmaxf(m_fg, lv);
        }
        float denom = 0.f;
        for (int c = 0; c < CC_; ++c) denom += expf(sm.Ssc[tid][c] - m_all);
        const float maxsc = expf(m_fg - m_all) / denom;
        if (maxsc > PRE_TH) {
            const int pos = atomicAdd(nrowsp, 1);
            rowlist[pos] = row0 + tid;
        }
    }
}

// ---------------------------------------------------------------------------
// Kernel 1b: fp64 logits on gathered rows. 8 rows/block x 2000 blocks,
// 512 threads split-K=2 (1 row x 3 cols per thread). Per-output fp64
// arithmetic identical to R12 (same products, same k-order, lo+hi combine).
// Wave-parallel softmax (1 wave/row, fixed-tree denom).
// ---------------------------------------------------------------------------
__global__ __launch_bounds__(512) void logits_fp64_rows(
    const float* __restrict__ A, const float* __restrict__ Wc,
    const float* __restrict__ bc,
    const int* __restrict__ rowlist, const int* __restrict__ nrowsp,
    float* __restrict__ cs, int* __restrict__ clab,
    int* __restrict__ corig, int* __restrict__ cpidx,
    int* __restrict__ cnt)
{
    const int nr = *nrowsp;
    const int row0 = blockIdx.x * 8;
    if (row0 >= nr) return;

    __shared__ __align__(16) float Af[2][16][12];   // 1.5 KB
    __shared__ __align__(16) float Bs[2][16][98];   // 12.5 KB
    __shared__ __align__(16) double dcomb[256][3];  // 6 KB
    __shared__ float Ssc[8][97];                    // 3.1 KB

    const int tid = threadIdx.x;
    const int kg = tid >> 8;
    const int l = tid & 255;
    const int kbase = kg * 512;
    const int r = l >> 5;              // row 0..7
    const int c0 = (l & 31) * 3;       // col base 0..93

    // A staging (l < 32): 8 rows x 16 k via float4
    const int aslot = l >> 2;          // 0..7
    const int akq = (l & 3) * 4;
    const float* Arow = nullptr;
    if (l < 32) {
        const int ridx = min(row0 + aslot, nr - 1);
        Arow = A + (size_t)rowlist[ridx] * FF_ + kbase;
    }
    // B staging: 16 k x 96 cols, 6 scalars
    const int bk = l >> 4;
    const int bn = (l & 15) * 6;

    double acc[3] = {0.0, 0.0, 0.0};

    float4 avP = make_float4(0.f, 0.f, 0.f, 0.f);
    if (l < 32) avP = *reinterpret_cast<const float4*>(Arow + akq);
    float bvP[6];
#pragma unroll
    for (int jj = 0; jj < 6; ++jj) {
        const int c = bn + jj;
        bvP[jj] = (c < CC_) ? Wc[(size_t)(kbase + bk) * CC_ + c] : 0.f;
    }

    for (int k0 = 0; k0 < 512; k0 += 16) {
        if (l < 32) {
            Af[kg][akq + 0][aslot] = avP.x;
            Af[kg][akq + 1][aslot] = avP.y;
            Af[kg][akq + 2][aslot] = avP.z;
            Af[kg][akq + 3][aslot] = avP.w;
        }
#pragma unroll
        for (int jj = 0; jj < 6; ++jj) Bs[kg][bk][bn + jj] = bvP[jj];

        const int kn = k0 + 16;
        if (kn < 512) {
            if (l < 32)
                avP = *reinterpret_cast<const float4*>(Arow + kn + akq);
#pragma unroll
            for (int jj = 0; jj < 6; ++jj) {
                const int c = bn + jj;
                bvP[jj] = (c < CC_) ? Wc[(size_t)(kbase + kn + bk) * CC_ + c] : 0.f;
            }
        }
        __syncthreads();

#pragma unroll
        for (int k = 0; k < 16; ++k) {
            const double a0 = (double)Af[kg][k][r];
            const double b0 = (double)Bs[kg][k][c0 + 0];
            const double b1 = (double)Bs[kg][k][c0 + 1];
            const double b2 = (double)Bs[kg][k][c0 + 2];
            acc[0] += a0 * b0;
            acc[1] += a0 * b1;
            acc[2] += a0 * b2;
        }
        __syncthreads();
    }

    // fixed-order combine lo+hi
    if (kg == 1) {
#pragma unroll
        for (int j = 0; j < 3; ++j) dcomb[l][j] = acc[j];
    }
    __syncthreads();
    if (kg == 0) {
#pragma unroll
        for (int j = 0; j < 3; ++j) {
            const int c = c0 + j;
            if (c < CC_) {
                const double v = acc[j] + dcomb[l][j];
                Ssc[r][c] = __fadd_rn((float)v, bc[c]);
            }
        }
    }
    __syncthreads();

    // wave-parallel softmax: wave w -> row w; lane covers cols lane, lane+64
    {
        const int w = tid >> 6;        // 0..7
        if (w < 8 && row0 + w < nr) {
            const int lane = tid & 63;
            const int p = rowlist[row0 + w];
            const int b = p / PP_;
            const int pi = p - b * PP_;

            const float l1 = Ssc[w][lane];                       // lane < 91
            const float l2 = (lane < CC_ - 64) ? Ssc[w][lane + 64] : -INFINITY;
            float m = fmaxf(l1, l2);
#pragma unroll
            for (int off = 32; off > 0; off >>= 1)
                m = fmaxf(m, __shfl_xor(m, off));

            double d = exp((double)l1 - (double)m);
            if (lane < CC_ - 64) d += exp((double)l2 - (double)m);
#pragma unroll
            for (int off = 1; off < 64; off <<= 1)
                d += __shfl_xor(d, off);

            // emit candidates (c >= 1 only)
#pragma unroll
            for (int q = 0; q < 2; ++q) {
                const int c = lane + q * 64;
                if (c >= 1 && c < CC_) {
                    const double sd = exp((double)Ssc[w][c] - (double)m) / d;
                    const float score = (float)sd;
                    if (score > SCORE_TH) {
                        const int pos = atomicAdd(&cnt[b], 1);
                        if (pos < CAP_) {
                            const int g = b * CAP_ + pos;
                            cs[g] = score;
                            clab[g] = c;
                            corig[g] = pi * (CC_ - 1) + (c - 1);
                            cpidx[g] = p;
                        }
                    }
                }
            }
        }
    }
}

// ---------------------------------------------------------------------------
// Kernel 2: per-candidate box regression (FP64 dot) + strict-fp32 decode.
// Variant T uses transposed Wbt (coalesced); identical accumulation order.
// ---------------------------------------------------------------------------
template<bool USE_T>
__global__ __launch_bounds__(256) void decode_cand_k(
    const float* __restrict__ A, const float* __restrict__ Wb,
    const float* __restrict__ Wbt,
    const float* __restrict__ bb, const float* __restrict__ props,
    const int* __restrict__ cnt, const int* __restrict__ clab,
    const int* __restrict__ cpidx,
    float* __restrict__ cs, float* __restrict__ cx1, float* __restrict__ cy1,
    float* __restrict__ cx2, float* __restrict__ cy2)
{
    const int wid = (blockIdx.x * 256 + threadIdx.x) >> 6;
    const int lane = threadIdx.x & 63;
    const int b = wid / CAP_;
    const int pos = wid - b * CAP_;
    if (b >= BB_) return;
    const int n = min(cnt[b], CAP_);
    if (pos >= n) return;

    const int g = b * CAP_ + pos;
    const int p = cpidx[g];
    const int c = clab[g];

    const float* fr = A + (size_t)p * FF_;

    double a0 = 0.0, a1 = 0.0, a2 = 0.0, a3 = 0.0;
    if (USE_T) {
        const float* w0 = Wbt + (size_t)c * 4096;
        for (int k = lane; k < FF_; k += 64) {
            const double f = (double)fr[k];
            a0 += f * (double)w0[k];
            a1 += f * (double)w0[1024 + k];
            a2 += f * (double)w0[2048 + k];
            a3 += f * (double)w0[3072 + k];
        }
    } else {
        const float* wb0 = Wb + 4 * c;
        for (int k = lane; k < FF_; k += 64) {
            const double f = (double)fr[k];
            const float4 wv = *reinterpret_cast<const float4*>(wb0 + (size_t)k * (CC_ * 4));
            a0 += f * (double)wv.x; a1 += f * (double)wv.y;
            a2 += f * (double)wv.z; a3 += f * (double)wv.w;
        }
    }
#pragma unroll
    for (int off = 32; off > 0; off >>= 1) {
        a0 += __shfl_xor(a0, off);
        a1 += __shfl_xor(a1, off);
        a2 += __shfl_xor(a2, off);
        a3 += __shfl_xor(a3, off);
    }

    if (lane == 0) {
        const float dx = __fadd_rn((float)a0, bb[4 * c + 0]);
        const float dy = __fadd_rn((float)a1, bb[4 * c + 1]);
        const float clipf = (float)BBOX_CLIP_D;
        const float dw = fminf(__fadd_rn((float)a2, bb[4 * c + 2]), clipf);
        const float dh = fminf(__fadd_rn((float)a3, bb[4 * c + 3]), clipf);

        const float px1 = props[(size_t)p * 4 + 0];
        const float py1 = props[(size_t)p * 4 + 1];
        const float px2 = props[(size_t)p * 4 + 2];
        const float py2 = props[(size_t)p * 4 + 3];
        const float w = __fsub_rn(px2, px1);
        const float h = __fsub_rn(py2, py1);
        const float cx = __fadd_rn(px1, __fmul_rn(0.5f, w));
        const float cy = __fadd_rn(py1, __fmul_rn(0.5f, h));

        const float pcx = __fadd_rn(__fmul_rn(dx, w), cx);
        const float pcy = __fadd_rn(__fmul_rn(dy, h), cy);
        const float ew = (float)exp((double)dw);
        const float eh = (float)exp((double)dh);
        const float pw = __fmul_rn(ew, w);
        const float ph = __fmul_rn(eh, h);

        const float hw = __fmul_rn(0.5f, pw);
        const float hh = __fmul_rn(0.5f, ph);
        const float bx1 = fminf(fmaxf(__fsub_rn(pcx, hw), 0.f), IMG_W);
        const float by1 = fminf(fmaxf(__fsub_rn(pcy, hh), 0.f), IMG_H);
        const float bx2 = fminf(fmaxf(__fadd_rn(pcx, hw), 0.f), IMG_W);
        const float by2 = fminf(fmaxf(__fadd_rn(pcy, hh), 0.f), IMG_H);

        cx1[g] = bx1; cy1[g] = by1; cx2[g] = bx2; cy2[g] = by2;
        if (!(__fsub_rn(bx2, bx1) >= MIN_SZ && __fsub_rn(by2, by1) >= MIN_SZ)) {
            cs[g] = -INFINITY;
        }
    }
}

// ---------------------------------------------------------------------------
// Kernel 3: per-(image,class) greedy NMS — one wave per (b,c) pair.
// (unchanged — bit-exact)
// ---------------------------------------------------------------------------
__global__ __launch_bounds__(64) void nms_class(
    const float* __restrict__ c_x1, const float* __restrict__ c_y1,
    const float* __restrict__ c_x2, const float* __restrict__ c_y2,
    const float* __restrict__ c_s, const int* __restrict__ c_lab,
    const int* __restrict__ c_orig, const int* __restrict__ cnt,
    ull* __restrict__ skey, float* __restrict__ sx1v, float* __restrict__ sy1v,
    float* __restrict__ sx2v, float* __restrict__ sy2v,
    int* __restrict__ slabv, int* __restrict__ scnt)
{
    const int blk = blockIdx.x;
    const int b = blk / (CC_ - 1);
    const int c = 1 + (blk - b * (CC_ - 1));
    const int lane = threadIdx.x;

    __shared__ ull kk[CLS_CAP];
    __shared__ float x1s[CLS_CAP], y1s[CLS_CAP], x2s[CLS_CAP], y2s[CLS_CAP];

    const int n = min(cnt[b], CAP_);

    int mcnt = 0;
    for (int i0 = 0; i0 < n; i0 += 64) {
        const int i = i0 + lane;
        bool take = false;
        float s = 0.f; int so = 0; int g = 0;
        if (i < n) {
            g = b * CAP_ + i;
            if (c_lab[g] == c) {
                s = c_s[g];
                if (s > 0.f) { take = true; so = c_orig[g]; }
            }
        }
        const ull bal = __ballot(take);
        if (take) {
            const int pos = mcnt + __popcll(bal & ((1ull << lane) - 1ull));
            if (pos < CLS_CAP) {
                kk[pos] = ((ull)__float_as_uint(s) << 32) |
                          (unsigned int)(0x7FFFFFFF - so);
                x1s[pos] = c_x1[g]; y1s[pos] = c_y1[g];
                x2s[pos] = c_x2[g]; y2s[pos] = c_y2[g];
            }
        }
        mcnt += (int)__popcll(bal);
    }
    mcnt = min(mcnt, CLS_CAP);
    if (mcnt == 0) return;
    __syncthreads();

    while (true) {
        ull best = 0ull;
        for (int i = lane; i < mcnt; i += 64) best = (kk[i] > best) ? kk[i] : best;
#pragma unroll
        for (int off = 32; off > 0; off >>= 1) {
            const ull o = __shfl_xor(best, off);
            best = (o > best) ? o : best;
        }
        if (best == 0ull) break;

        int wsl = -1;
        for (int i = lane; i < mcnt; i += 64) if (kk[i] == best) wsl = i;
        const ull bal = __ballot(wsl >= 0);
        const int wlane = (int)__ffsll((long long)bal) - 1;
        wsl = __shfl(wsl, wlane);

        const float wx1 = x1s[wsl], wy1 = y1s[wsl];
        const float wx2 = x2s[wsl], wy2 = y2s[wsl];

        if (lane == 0) {
            const int sp = atomicAdd(&scnt[b], 1);
            if (sp < SURV_CAP) {
                const int sg = b * SURV_CAP + sp;
                skey[sg] = best;
                sx1v[sg] = wx1; sy1v[sg] = wy1;
                sx2v[sg] = wx2; sy2v[sg] = wy2;
                slabv[sg] = c;
            }
        }

        const float off = __fmul_rn((float)c, OFF_);
        const float ax1 = __fadd_rn(wx1, off), ay1 = __fadd_rn(wy1, off);
        const float ax2 = __fadd_rn(wx2, off), ay2 = __fadd_rn(wy2, off);
        const float a1 = __fmul_rn(__fsub_rn(ax2, ax1), __fsub_rn(ay2, ay1));
        for (int i = lane; i < mcnt; i += 64) {
            if (kk[i] == 0ull) continue;
            const float bx1 = __fadd_rn(x1s[i], off), by1 = __fadd_rn(y1s[i], off);
            const float bx2 = __fadd_rn(x2s[i], off), by2 = __fadd_rn(y2s[i], off);
            const float ix1 = fmaxf(ax1, bx1), iy1 = fmaxf(ay1, by1);
            const float ix2 = fminf(ax2, bx2), iy2 = fminf(ay2, by2);
            const float inter = __fmul_rn(fmaxf(__fsub_rn(ix2, ix1), 0.f),
                                          fmaxf(__fsub_rn(iy2, iy1), 0.f));
            const float a2 = __fmul_rn(__fsub_rn(bx2, bx1), __fsub_rn(by2, by1));
            const float den = __fadd_rn(__fsub_rn(__fadd_rn(a1, a2), inter), 1e-9f);
            const float iou = __fdiv_rn(inter, den);
            if (iou > NMS_TH) kk[i] = 0ull;
        }
        __syncthreads();
    }
}

// ---------------------------------------------------------------------------
// Kernel 4: per-image merge — bitonic sort survivors by key (desc), emit
// top-100 in order. (unchanged — bit-exact)
// ---------------------------------------------------------------------------
__global__ __launch_bounds__(256) void nms_merge(
    const ull* __restrict__ skey, const float* __restrict__ sx1v,
    const float* __restrict__ sy1v, const float* __restrict__ sx2v,
    const float* __restrict__ sy2v, const int* __restrict__ slabv,
    const int* __restrict__ scnt, float* __restrict__ out)
{
    const int b = blockIdx.x;
    const int t = threadIdx.x;

    __shared__ ull k_[SURV_CAP];
    __shared__ int id_[SURV_CAP];

    const int m = min(scnt[b], SURV_CAP);
    int N2 = 128;
    while (N2 < m) N2 <<= 1;

    for (int i = t; i < N2; i += 256) {
        k_[i] = (i < m) ? skey[b * SURV_CAP + i] : 0ull;
        id_[i] = i;
    }
    __syncthreads();

    for (int ksz = 2; ksz <= N2; ksz <<= 1) {
        for (int j = ksz >> 1; j > 0; j >>= 1) {
            for (int i = t; i < N2; i += 256) {
                const int ixj = i ^ j;
                if (ixj > i) {
                    const ull a = k_[i], cc = k_[ixj];
                    const bool desc = ((i & ksz) == 0);
                    if (desc ? (a < cc) : (a > cc)) {
                        k_[i] = cc; k_[ixj] = a;
                        const int tmp = id_[i]; id_[i] = id_[ixj]; id_[ixj] = tmp;
                    }
                }
            }
            __syncthreads();
        }
    }

    const int boxes_base = 0;
    const int scores_base = BB_ * DETS_ * 4;
    const int labels_base = BB_ * DETS_ * 5;

    for (int r = t; r < DETS_; r += 256) {
        const ull key = (r < N2) ? k_[r] : 0ull;
        float* bo = out + boxes_base + (size_t)(b * DETS_ + r) * 4;
        if (key != 0ull) {
            const int sg = b * SURV_CAP + id_[r];
            bo[0] = sx1v[sg]; bo[1] = sy1v[sg];
            bo[2] = sx2v[sg]; bo[3] = sy2v[sg];
            out[scores_base + b * DETS_ + r] = __uint_as_float((unsigned)(key >> 32));
            out[labels_base + b * DETS_ + r] = (float)slabv[sg];
        } else {
            bo[0] = 0.f; bo[1] = 0.f; bo[2] = 0.f; bo[3] = 0.f;
            out[scores_base + b * DETS_ + r] = 0.f;
            out[labels_base + b * DETS_ + r] = 0.f;
        }
    }
}

// ---------------------------------------------------------------------------
extern "C" void kernel_launch(void* const* d_in, const int* in_sizes, int n_in,
                              void* d_out, int out_size, void* d_ws, size_t ws_size,
                              hipStream_t stream)
{
    const float* feat  = (const float*)d_in[0];
    const float* Wc    = (const float*)d_in[1];
    const float* bc    = (const float*)d_in[2];
    const float* Wb    = (const float*)d_in[3];
    const float* bb    = (const float*)d_in[4];
    const float* props = (const float*)d_in[5];
    for (int i = 0; i < n_in; ++i) {
        const float* q = (const float*)d_in[i];
        switch (in_sizes[i]) {
            case 16384000: feat  = q; break;  // [16000,1024]
            case 93184:    Wc    = q; break;  // [1024,91]
            case 91:       bc    = q; break;
            case 372736:   Wb    = q; break;  // [1024,364]
            case 364:      bb    = q; break;
            case 64000:    props = q; break;  // [16,1000,4]
        }
    }
    float* out = (float*)d_out;

    char* ws = (char*)d_ws;
    int*   cnt    = (int*)ws;            // 16 ints
    int*   scnt   = (int*)(ws + 64);     // 16 ints
    int*   nrowsp = (int*)(ws + 128);    // 1 int
    float* cs    = (float*)(ws + 256);
    int*   clab  = (int*)(cs + CAND_MAX);
    int*   corig = clab + CAND_MAX;
    int*   cpidx = corig + CAND_MAX;
    float* cx1   = (float*)(cpidx + CAND_MAX);
    float* cy1   = cx1 + CAND_MAX;
    float* cx2   = cy1 + CAND_MAX;
    float* cy2   = cx2 + CAND_MAX;
    ull*   skey  = (ull*)(cy2 + CAND_MAX);
    float* sx1v  = (float*)(skey + (size_t)BB_ * SURV_CAP);
    float* sy1v  = sx1v + (size_t)BB_ * SURV_CAP;
    float* sx2v  = sy1v + (size_t)BB_ * SURV_CAP;
    float* sy2v  = sx2v + (size_t)BB_ * SURV_CAP;
    int*   slabv = (int*)(sy2v + (size_t)BB_ * SURV_CAP);
    int*   rowlist = slabv + (size_t)BB_ * SURV_CAP;   // 16000 ints
    float* Wbt   = (float*)(rowlist + 16384);          // 91*4*1024 floats

    const size_t need = ((char*)(Wbt + CC_ * 4 * FF_)) - ws;
    const bool useT = (ws_size >= need);

    hipMemsetAsync(ws, 0, 256, stream);   // zero cnt + scnt + nrows

    if (useT)
        wb_transpose<<<(CC_ * 4 * FF_ + 255) / 256, 256, 0, stream>>>(Wb, Wbt);

    prepass_rows<<<BB_ * PP_ / 32, 512, 0, stream>>>(feat, Wc, bc,
        rowlist, nrowsp);

    logits_fp64_rows<<<BB_ * PP_ / 8, 512, 0, stream>>>(feat, Wc, bc,
        rowlist, nrowsp, cs, clab, corig, cpidx, cnt);

    if (useT)
        decode_cand_k<true><<<CAND_MAX / 4, 256, 0, stream>>>(feat, Wb, Wbt,
            bb, props, cnt, clab, cpidx, cs, cx1, cy1, cx2, cy2);
    else
        decode_cand_k<false><<<CAND_MAX / 4, 256, 0, stream>>>(feat, Wb, Wbt,
            bb, props, cnt, clab, cpidx, cs, cx1, cy1, cx2, cy2);

    nms_class<<<BB_ * (CC_ - 1), 64, 0, stream>>>(
        cx1, cy1, cx2, cy2, cs, clab, corig, cnt,
        skey, sx1v, sy1v, sx2v, sy2v, slabv, scnt);

    nms_merge<<<BB_, 256, 0, stream>>>(
        skey, sx1v, sy1v, sx2v, sy2v, slabv, scnt, out);
}